// Round 6
// baseline (352.190 us; speedup 1.0000x reference)
//
#include <hip/hip_runtime.h>

#define NN   50000
#define NE   800000
#define INF  128
#define EF   32
#define OUTF 128
#define KDIM 288   // 128 (h) + 128 (mean_h) + 32 (mean_e)
#define NBLK ((NN + 1023) / 1024)   // 49 scan blocks

typedef __attribute__((ext_vector_type(8))) short          short8;   // 8 bf16
typedef __attribute__((ext_vector_type(8))) unsigned short ushort8;
typedef __attribute__((ext_vector_type(4))) unsigned short ushort4v;
typedef __attribute__((ext_vector_type(4))) float          float4v;

__device__ __forceinline__ unsigned short f2bf(float f) {
    union { float f; unsigned int u; } c; c.f = f;
    const unsigned int r = (c.u + 0x7FFFu + ((c.u >> 16) & 1u)) >> 16;
    return (unsigned short)r;
}

// ---------------------------------------------------------------------------
// Fused prep+pack: build Mb (bf16 MFMA B-frag order, [kb(9)][ct(8)][lane][8])
// directly from weight/W_w, plus cvec. Fragment: B[k=quad*8+i][n=lane&15].
//   k < 128  : M[k][col]      = W_w[col][k]
//   k >= 128 : M[k][col]      = sum_c weight[k-128][c] * W_w[col][128+c]
//   cvec[j] = W_b[j] + bias[j]
// grid = 73 blocks x 64 threads (block 72 does cvec).
// ---------------------------------------------------------------------------
__global__ void prep_pack_kernel(const float* __restrict__ weight,
                                 const float* __restrict__ W_w,
                                 const float* __restrict__ W_b,
                                 const float* __restrict__ bias,
                                 unsigned short* __restrict__ Mb,
                                 float* __restrict__ cvec) {
    const int b = blockIdx.x;
    const int lane = threadIdx.x;
    if (b == 72) {
        cvec[lane]      = W_b[lane]      + bias[lane];
        cvec[lane + 64] = W_b[lane + 64] + bias[lane + 64];
        return;
    }
    const int kb = b >> 3;
    const int ct = b & 7;
    const int col = ct * 16 + (lane & 15);
    const int k0 = kb * 32 + (lane >> 4) * 8;
    ushort8 v;
#pragma unroll
    for (int i = 0; i < 8; ++i) {
        const int k = k0 + i;
        float val;
        if (k < 128) {
            val = W_w[(size_t)col * 256 + k];
        } else {
            const float4* wr  = (const float4*)(weight + (size_t)(k - 128) * OUTF);
            const float4* wwr = (const float4*)(W_w + (size_t)col * 256 + 128);
            float acc = 0.f;
#pragma unroll 4
            for (int c = 0; c < 32; ++c) {
                const float4 a = wr[c], bb = wwr[c];
                acc += a.x * bb.x + a.y * bb.y + a.z * bb.z + a.w * bb.w;
            }
            val = acc;
        }
        v[i] = f2bf(val);
    }
    *(ushort8*)(Mb + ((size_t)(b * 64 + lane) * 8)) = v;
}

// ---------------------------------------------------------------------------
// CSR build step 1: histogram of dst (pre-zeroed off), int4-vectorized reads.
// ---------------------------------------------------------------------------
__global__ __launch_bounds__(256)
void hist_kernel(const int* __restrict__ dst, int* __restrict__ off) {
    const int e = (blockIdx.x * 256 + threadIdx.x) * 4;
    if (e + 3 < NE) {
        const int4 d = *(const int4*)(dst + e);
        atomicAdd(&off[d.x], 1);
        atomicAdd(&off[d.y], 1);
        atomicAdd(&off[d.z], 1);
        atomicAdd(&off[d.w], 1);
    } else {
        for (int i = e; i < NE; ++i) atomicAdd(&off[dst[i]], 1);
    }
}

// ---------------------------------------------------------------------------
// Scan phase 1: per-block (1024 elems) sum -> partial[b]
// ---------------------------------------------------------------------------
__global__ __launch_bounds__(256)
void scan1_kernel(const int* __restrict__ off, int* __restrict__ partial) {
    const int b = blockIdx.x;
    const int tid = threadIdx.x;
    const int idx = b * 1024 + tid * 4;
    int v0 = 0, v1 = 0, v2 = 0, v3 = 0;
    if (idx + 3 < NN) {
        const int4 q = *(const int4*)(off + idx);
        v0 = q.x; v1 = q.y; v2 = q.z; v3 = q.w;
    } else {
        if (idx + 0 < NN) v0 = off[idx + 0];
        if (idx + 1 < NN) v1 = off[idx + 1];
        if (idx + 2 < NN) v2 = off[idx + 2];
    }
    int t = v0 + v1 + v2 + v3;
#pragma unroll
    for (int ofs = 32; ofs > 0; ofs >>= 1) t += __shfl_down(t, ofs);
    __shared__ int wsum[4];
    if ((tid & 63) == 0) wsum[tid >> 6] = t;
    __syncthreads();
    if (tid == 0) partial[b] = wsum[0] + wsum[1] + wsum[2] + wsum[3];
}

// ---------------------------------------------------------------------------
// Scan phase 2+3 fused: each block re-scans the 49 partials (one wave),
// then local exclusive scan + in-place rewrite of off.
// ---------------------------------------------------------------------------
__global__ __launch_bounds__(256)
void scan3_kernel(int* __restrict__ off, const int* __restrict__ partial) {
    __shared__ int blockbase;
    __shared__ int wsum[4];
    const int b = blockIdx.x;
    const int tid = threadIdx.x;
    const int lane = tid & 63;
    const int wid = tid >> 6;

    if (wid == 0) {
        const int v = (lane < NBLK) ? partial[lane] : 0;
        int x = v;
#pragma unroll
        for (int ofs = 1; ofs < 64; ofs <<= 1) {
            const int t = __shfl_up(x, ofs);
            if (lane >= ofs) x += t;
        }
        if (lane == b) blockbase = x - v;
    }

    const int idx = b * 1024 + tid * 4;
    int v0 = 0, v1 = 0, v2 = 0, v3 = 0;
    if (idx + 3 < NN) {
        const int4 q = *(const int4*)(off + idx);
        v0 = q.x; v1 = q.y; v2 = q.z; v3 = q.w;
    } else {
        if (idx + 0 < NN) v0 = off[idx + 0];
        if (idx + 1 < NN) v1 = off[idx + 1];
        if (idx + 2 < NN) v2 = off[idx + 2];
    }
    const int tsum = v0 + v1 + v2 + v3;
    int x = tsum;
#pragma unroll
    for (int ofs = 1; ofs < 64; ofs <<= 1) {
        const int t = __shfl_up(x, ofs);
        if (lane >= ofs) x += t;
    }
    if (lane == 63) wsum[wid] = x;
    __syncthreads();
    int wp = 0;
    for (int w = 0; w < wid; ++w) wp += wsum[w];
    const int base = blockbase + wp + (x - tsum);
    if (idx + 0 < NN) off[idx + 0] = base;
    if (idx + 1 < NN) off[idx + 1] = base + v0;
    if (idx + 2 < NN) off[idx + 2] = base + v0 + v1;
    if (idx + 3 < NN) off[idx + 3] = base + v0 + v1 + v2;
}

// ---------------------------------------------------------------------------
// CSR build step 3: scatter {src,edge}. Cursor trick: afterwards off[d] is
// the END offset of segment d (start = off[d-1]).
// ---------------------------------------------------------------------------
__global__ __launch_bounds__(256)
void scatter_ids_kernel(const int* __restrict__ srcv,
                        const int* __restrict__ dst,
                        int* __restrict__ off,
                        int2* __restrict__ eo2) {
    const int e = blockIdx.x * 256 + threadIdx.x;
    if (e < NE) {
        const int d = dst[e];
        const int pos = atomicAdd(&off[d], 1);
        eo2[pos] = make_int2(srcv[e], e);
    }
}

// ---------------------------------------------------------------------------
// Gather: one wave per node; all loads are float4 (16 B/lane, the coalescing
// sweet spot). h: 2 edges/step via half-waves (lanes 0-31 = even edge, 32-63
// = odd edge, cols (lane&31)*4). eftr: 8 edges/step via 8-lane groups (group
// g = edge j+g, cols (lane&7)*4). shfl_xor folds at the end. Outputs bf16.
// ---------------------------------------------------------------------------
__global__ __launch_bounds__(256)
void gather_kernel(const float* __restrict__ h,
                   const float* __restrict__ eftr,
                   const int* __restrict__ off,   // end offsets
                   const int2* __restrict__ eo2,
                   unsigned short* __restrict__ mean_h,   // bf16 [NN][128]
                   unsigned short* __restrict__ mean_e) { // bf16 [NN][32]
    const int tid = threadIdx.x;
    const int lane = tid & 63;
    const int node = blockIdx.x * 4 + (tid >> 6);
    if (node >= NN) return;

    const int end = off[node];
    const int start = (node == 0) ? 0 : off[node - 1];

    const int half = lane >> 5;          // h: which edge of the pair
    const int hcol = (lane & 31) * 4;    // h cols
    const int g = lane >> 3;             // eftr: edge group 0..7
    const int ecol = (lane & 7) * 4;     // eftr cols

    float4 ah = make_float4(0.f, 0.f, 0.f, 0.f);
    float4 ae = make_float4(0.f, 0.f, 0.f, 0.f);

    for (int base = start; base < end; base += 64) {
        const int m = min(64, end - base);
        int px = 0, py = 0;
        if (base + lane < end) {
            const long long pv =
                __builtin_nontemporal_load((const long long*)(eo2 + base + lane));
            px = (int)pv;
            py = (int)(pv >> 32);
        }
        for (int j = 0; j < m; j += 8) {
            float4 hv[4];
            bool hok[4];
#pragma unroll
            for (int u = 0; u < 4; ++u) {
                const int ei = j + 2 * u + half;
                const int s = __shfl(px, ei);          // bpermute (per-lane idx)
                hv[u] = *(const float4*)(h + (size_t)s * INF + hcol);
                hok[u] = (ei < m);
            }
            const int ee = __shfl(py, j + g);
            const float4 fv = *(const float4*)(eftr + (size_t)ee * EF + ecol);
            const bool eok = (j + g < m);
#pragma unroll
            for (int u = 0; u < 4; ++u)
                if (hok[u]) {
                    ah.x += hv[u].x; ah.y += hv[u].y;
                    ah.z += hv[u].z; ah.w += hv[u].w;
                }
            if (eok) {
                ae.x += fv.x; ae.y += fv.y; ae.z += fv.z; ae.w += fv.w;
            }
        }
    }

    // fold: h halves (xor 32); eftr groups (xor 8,16,32)
    ah.x += __shfl_xor(ah.x, 32); ah.y += __shfl_xor(ah.y, 32);
    ah.z += __shfl_xor(ah.z, 32); ah.w += __shfl_xor(ah.w, 32);
#pragma unroll
    for (int d = 8; d <= 32; d <<= 1) {
        ae.x += __shfl_xor(ae.x, d); ae.y += __shfl_xor(ae.y, d);
        ae.z += __shfl_xor(ae.z, d); ae.w += __shfl_xor(ae.w, d);
    }

    const float inv = 1.f / fmaxf((float)(end - start), 1.f);
    if (lane < 32) {
        ushort4v o;
        o[0] = f2bf(ah.x * inv); o[1] = f2bf(ah.y * inv);
        o[2] = f2bf(ah.z * inv); o[3] = f2bf(ah.w * inv);
        *(ushort4v*)(mean_h + (size_t)node * INF + hcol) = o;
    }
    if (lane < 8) {
        ushort4v o;
        o[0] = f2bf(ae.x * inv); o[1] = f2bf(ae.y * inv);
        o[2] = f2bf(ae.z * inv); o[3] = f2bf(ae.w * inv);
        *(ushort4v*)(mean_e + (size_t)node * EF + ecol) = o;
    }
}

// ---------------------------------------------------------------------------
// Node GEMM via MFMA (bf16 in, fp32 acc). LDS-free, barrier-free.
// Wave owns 16 nodes x 128 cols, K=288 in 9 chunks. A-frag k-range is
// contiguous: fp32 h (convert) for kb<4, direct b128 bf16 loads for kb>=4.
// ---------------------------------------------------------------------------
__global__ __launch_bounds__(256)
void node_gemm_kernel(const float* __restrict__ h,
                      const unsigned short* __restrict__ mean_h,
                      const unsigned short* __restrict__ mean_e,
                      const unsigned short* __restrict__ Mb,
                      const float* __restrict__ cvec,
                      float* __restrict__ out) {
    const int tid = threadIdx.x;
    const int lane = tid & 63;
    const int wid = tid >> 6;
    const int nt = blockIdx.x * 4 + wid;     // 16-node tile id
    const int m16 = lane & 15;
    const int quad = lane >> 4;
    const int koff = quad * 8;

    const int anode = nt * 16 + m16;
    const int nclamp = (anode < NN) ? anode : (NN - 1);

    float4v acc[8] = {};

    for (int kb = 0; kb < 9; ++kb) {
        short8 a;
        if (kb < 4) {
            const float* srcp = h + (size_t)nclamp * INF + kb * 32 + koff;
            const float4 p0 = *(const float4*)srcp;
            const float4 p1 = *(const float4*)(srcp + 4);
            a[0] = (short)f2bf(p0.x); a[1] = (short)f2bf(p0.y);
            a[2] = (short)f2bf(p0.z); a[3] = (short)f2bf(p0.w);
            a[4] = (short)f2bf(p1.x); a[5] = (short)f2bf(p1.y);
            a[6] = (short)f2bf(p1.z); a[7] = (short)f2bf(p1.w);
        } else if (kb < 8) {
            a = *(const short8*)(mean_h + (size_t)nclamp * INF + (kb - 4) * 32 + koff);
        } else {
            a = *(const short8*)(mean_e + (size_t)nclamp * EF + koff);
        }

        const short8* bp = (const short8*)(Mb + (size_t)kb * 8 * 64 * 8);
#pragma unroll
        for (int ct = 0; ct < 8; ++ct) {
            const short8 b = bp[ct * 64 + lane];
            acc[ct] = __builtin_amdgcn_mfma_f32_16x16x32_bf16(a, b, acc[ct], 0, 0, 0);
        }
    }

    float cv[8];
#pragma unroll
    for (int ct = 0; ct < 8; ++ct) cv[ct] = cvec[ct * 16 + m16];

#pragma unroll
    for (int r = 0; r < 4; ++r) {
        const int nrow = nt * 16 + quad * 4 + r;
        if (nrow < NN) {
            float* orow = out + (size_t)nrow * OUTF;
#pragma unroll
            for (int ct = 0; ct < 8; ++ct)
                orow[ct * 16 + m16] = acc[ct][r] + cv[ct];
        }
    }
}

extern "C" void kernel_launch(void* const* d_in, const int* in_sizes, int n_in,
                              void* d_out, int out_size, void* d_ws, size_t ws_size,
                              hipStream_t stream) {
    const float* h      = (const float*)d_in[0];
    const float* eftr   = (const float*)d_in[1];
    const float* weight = (const float*)d_in[2];
    const float* W_w    = (const float*)d_in[3];
    const float* W_b    = (const float*)d_in[4];
    const float* bias   = (const float*)d_in[5];
    const int*   src    = (const int*)d_in[6];
    const int*   dst    = (const int*)d_in[7];
    float* out = (float*)d_out;

    // workspace layout:
    char* p = (char*)d_ws;
    unsigned short* mean_h = (unsigned short*)p;  p += (size_t)NN * INF * 2;  // 12.8 MB
    unsigned short* mean_e = (unsigned short*)p;  p += (size_t)NN * EF * 2;   // 3.2 MB
    unsigned short* Mb     = (unsigned short*)p;  p += (size_t)KDIM * OUTF * 2; // 73728 B
    float*          cvec   = (float*)p;          p += OUTF * 4;
    int*            off    = (int*)p;            p += (size_t)NN * 4;
    int2*           eo2    = (int2*)p;           p += (size_t)NE * 8;
    int*            partial= (int*)p;
    // total ≈ 22.8 MB

    hipMemsetAsync(off, 0, (size_t)NN * sizeof(int), stream);

    prep_pack_kernel<<<73, 64, 0, stream>>>(weight, W_w, W_b, bias, Mb, cvec);
    hist_kernel<<<(NE / 4 + 255) / 256, 256, 0, stream>>>(dst, off);
    scan1_kernel<<<NBLK, 256, 0, stream>>>(off, partial);
    scan3_kernel<<<NBLK, 256, 0, stream>>>(off, partial);
    scatter_ids_kernel<<<(NE + 255) / 256, 256, 0, stream>>>(src, dst, off, eo2);
    gather_kernel<<<(NN + 3) / 4, 256, 0, stream>>>(h, eftr, off, eo2,
                                                    mean_h, mean_e);
    node_gemm_kernel<<<(NN / 64) + 1, 256, 0, stream>>>(h, mean_h, mean_e,
                                                        Mb, cvec, out);
}

// Round 7
// 343.294 us; speedup vs baseline: 1.0259x; 1.0259x over previous
//
#include <hip/hip_runtime.h>

#define NN   50000
#define NE   800000
#define INF  128
#define EF   32
#define OUTF 128
#define KDIM 288   // 128 (h) + 128 (mean_h) + 32 (mean_e)
#define NBLK ((NN + 1023) / 1024)   // 49 scan blocks

typedef __attribute__((ext_vector_type(8))) short          short8;   // 8 bf16
typedef __attribute__((ext_vector_type(8))) unsigned short ushort8;
typedef __attribute__((ext_vector_type(4))) unsigned short ushort4v;
typedef __attribute__((ext_vector_type(4))) float          float4v;

__device__ __forceinline__ unsigned short f2bf(float f) {
    union { float f; unsigned int u; } c; c.f = f;
    const unsigned int r = (c.u + 0x7FFFu + ((c.u >> 16) & 1u)) >> 16;
    return (unsigned short)r;
}
__device__ __forceinline__ float bf2f(unsigned short u) {
    union { unsigned int u; float f; } c; c.u = ((unsigned int)u) << 16;
    return c.f;
}

// ---------------------------------------------------------------------------
// h fp32 -> bf16 (one-time). 8 elems/thread. grid = 3125 x 256 exactly.
// ---------------------------------------------------------------------------
__global__ __launch_bounds__(256)
void h2bf_kernel(const float* __restrict__ h, unsigned short* __restrict__ hb) {
    const size_t i = ((size_t)blockIdx.x * 256 + threadIdx.x) * 8;
    const float4 a = *(const float4*)(h + i);
    const float4 b = *(const float4*)(h + i + 4);
    ushort8 o;
    o[0] = f2bf(a.x); o[1] = f2bf(a.y); o[2] = f2bf(a.z); o[3] = f2bf(a.w);
    o[4] = f2bf(b.x); o[5] = f2bf(b.y); o[6] = f2bf(b.z); o[7] = f2bf(b.w);
    *(ushort8*)(hb + i) = o;
}

// ---------------------------------------------------------------------------
// Fused prep+pack (+ off zeroing in extra blocks): build Mb (bf16 B-frag
// order [kb(9)][ct(8)][lane][8], B[k=quad*8+i][n=lane&15]) and cvec.
//   k < 128  : M[k][col] = W_w[col][k]
//   k >= 128 : M[k][col] = sum_c weight[k-128][c] * W_w[col][128+c]
// grid = 269 x 64: blocks 0..71 pack, 72 does cvec, 73..268 zero off.
// ---------------------------------------------------------------------------
__global__ void prep_pack_kernel(const float* __restrict__ weight,
                                 const float* __restrict__ W_w,
                                 const float* __restrict__ W_b,
                                 const float* __restrict__ bias,
                                 unsigned short* __restrict__ Mb,
                                 float* __restrict__ cvec,
                                 int* __restrict__ off) {
    const int b = blockIdx.x;
    const int lane = threadIdx.x;
    if (b >= 73) {
        const int idx = ((b - 73) * 64 + lane) * 4;
        if (idx + 3 < NN) {
            *(int4*)(off + idx) = make_int4(0, 0, 0, 0);
        } else {
            for (int i = idx; i < NN; ++i) off[i] = 0;
        }
        return;
    }
    if (b == 72) {
        cvec[lane]      = W_b[lane]      + bias[lane];
        cvec[lane + 64] = W_b[lane + 64] + bias[lane + 64];
        return;
    }
    const int kb = b >> 3;
    const int ct = b & 7;
    const int col = ct * 16 + (lane & 15);
    const int k0 = kb * 32 + (lane >> 4) * 8;
    ushort8 v;
#pragma unroll
    for (int i = 0; i < 8; ++i) {
        const int k = k0 + i;
        float val;
        if (k < 128) {
            val = W_w[(size_t)col * 256 + k];
        } else {
            const float4* wr  = (const float4*)(weight + (size_t)(k - 128) * OUTF);
            const float4* wwr = (const float4*)(W_w + (size_t)col * 256 + 128);
            float acc = 0.f;
#pragma unroll 4
            for (int c = 0; c < 32; ++c) {
                const float4 a = wr[c], bb = wwr[c];
                acc += a.x * bb.x + a.y * bb.y + a.z * bb.z + a.w * bb.w;
            }
            val = acc;
        }
        v[i] = f2bf(val);
    }
    *(ushort8*)(Mb + ((size_t)(b * 64 + lane) * 8)) = v;
}

// ---------------------------------------------------------------------------
// CSR build step 1: histogram of dst (off pre-zeroed by prep_pack).
// ---------------------------------------------------------------------------
__global__ __launch_bounds__(256)
void hist_kernel(const int* __restrict__ dst, int* __restrict__ off) {
    const int e = blockIdx.x * 256 + threadIdx.x;
    if (e < NE) atomicAdd(&off[dst[e]], 1);
}

// ---------------------------------------------------------------------------
// Scan phase 1: per-block (1024 elems) sum -> partial[b]
// ---------------------------------------------------------------------------
__global__ __launch_bounds__(256)
void scan1_kernel(const int* __restrict__ off, int* __restrict__ partial) {
    const int b = blockIdx.x;
    const int tid = threadIdx.x;
    const int idx = b * 1024 + tid * 4;
    int v0 = 0, v1 = 0, v2 = 0, v3 = 0;
    if (idx + 3 < NN) {
        const int4 q = *(const int4*)(off + idx);
        v0 = q.x; v1 = q.y; v2 = q.z; v3 = q.w;
    } else {
        if (idx + 0 < NN) v0 = off[idx + 0];
        if (idx + 1 < NN) v1 = off[idx + 1];
        if (idx + 2 < NN) v2 = off[idx + 2];
    }
    int t = v0 + v1 + v2 + v3;
#pragma unroll
    for (int ofs = 32; ofs > 0; ofs >>= 1) t += __shfl_down(t, ofs);
    __shared__ int wsum[4];
    if ((tid & 63) == 0) wsum[tid >> 6] = t;
    __syncthreads();
    if (tid == 0) partial[b] = wsum[0] + wsum[1] + wsum[2] + wsum[3];
}

// ---------------------------------------------------------------------------
// Scan phase 2+3 fused: each block re-scans the 49 partials (one wave),
// then local exclusive scan + in-place rewrite of off.
// ---------------------------------------------------------------------------
__global__ __launch_bounds__(256)
void scan3_kernel(int* __restrict__ off, const int* __restrict__ partial) {
    __shared__ int blockbase;
    __shared__ int wsum[4];
    const int b = blockIdx.x;
    const int tid = threadIdx.x;
    const int lane = tid & 63;
    const int wid = tid >> 6;

    if (wid == 0) {
        const int v = (lane < NBLK) ? partial[lane] : 0;
        int x = v;
#pragma unroll
        for (int ofs = 1; ofs < 64; ofs <<= 1) {
            const int t = __shfl_up(x, ofs);
            if (lane >= ofs) x += t;
        }
        if (lane == b) blockbase = x - v;
    }

    const int idx = b * 1024 + tid * 4;
    int v0 = 0, v1 = 0, v2 = 0, v3 = 0;
    if (idx + 3 < NN) {
        const int4 q = *(const int4*)(off + idx);
        v0 = q.x; v1 = q.y; v2 = q.z; v3 = q.w;
    } else {
        if (idx + 0 < NN) v0 = off[idx + 0];
        if (idx + 1 < NN) v1 = off[idx + 1];
        if (idx + 2 < NN) v2 = off[idx + 2];
    }
    const int tsum = v0 + v1 + v2 + v3;
    int x = tsum;
#pragma unroll
    for (int ofs = 1; ofs < 64; ofs <<= 1) {
        const int t = __shfl_up(x, ofs);
        if (lane >= ofs) x += t;
    }
    if (lane == 63) wsum[wid] = x;
    __syncthreads();
    int wp = 0;
    for (int w = 0; w < wid; ++w) wp += wsum[w];
    const int base = blockbase + wp + (x - tsum);
    if (idx + 0 < NN) off[idx + 0] = base;
    if (idx + 1 < NN) off[idx + 1] = base + v0;
    if (idx + 2 < NN) off[idx + 2] = base + v0 + v1;
    if (idx + 3 < NN) off[idx + 3] = base + v0 + v1 + v2;
}

// ---------------------------------------------------------------------------
// CSR build step 3: scatter {src,edge}. Cursor trick: afterwards off[d] is
// the END offset of segment d (start = off[d-1]).
// ---------------------------------------------------------------------------
__global__ __launch_bounds__(256)
void scatter_ids_kernel(const int* __restrict__ srcv,
                        const int* __restrict__ dst,
                        int* __restrict__ off,
                        int2* __restrict__ eo2) {
    const int e = blockIdx.x * 256 + threadIdx.x;
    if (e < NE) {
        const int d = dst[e];
        const int pos = atomicAdd(&off[d], 1);
        eo2[pos] = make_int2(srcv[e], e);
    }
}

// ---------------------------------------------------------------------------
// Gather: one wave per node, h in bf16 (halves gathered bytes — the
// delivered-BW bound). h: 16-lane groups, 4 edges per load instr (full
// 256 B row = 16 lanes x 16 B); per 8 edges: 2 h loads + 1 eftr load.
// Predicated via fma weights (shfl of unloaded lanes yields row 0 — must
// be masked). Folds: h xor16/32; eftr xor8/16/32. Outputs bf16 means.
// ---------------------------------------------------------------------------
__global__ __launch_bounds__(256)
void gather_kernel(const unsigned short* __restrict__ hb,
                   const float* __restrict__ eftr,
                   const int* __restrict__ off,   // end offsets
                   const int2* __restrict__ eo2,
                   unsigned short* __restrict__ mean_h,   // bf16 [NN][128]
                   unsigned short* __restrict__ mean_e) { // bf16 [NN][32]
    const int tid = threadIdx.x;
    const int lane = tid & 63;
    const int node = blockIdx.x * 4 + (tid >> 6);
    if (node >= NN) return;

    const int end = off[node];
    const int start = (node == 0) ? 0 : off[node - 1];

    const int gh = lane >> 4;            // h edge-group 0..3
    const int hcol = (lane & 15) * 8;    // 8 bf16 cols
    const int ge = lane >> 3;            // eftr edge-group 0..7
    const int ecol = (lane & 7) * 4;     // 4 fp32 cols

    float ah[8] = {};
    float4 ae = make_float4(0.f, 0.f, 0.f, 0.f);

    for (int base = start; base < end; base += 64) {
        const int m = min(64, end - base);
        int px = 0, py = 0;
        if (base + lane < end) {
            const long long pv =
                __builtin_nontemporal_load((const long long*)(eo2 + base + lane));
            px = (int)pv;
            py = (int)(pv >> 32);
        }
        for (int j = 0; j < m; j += 8) {
            const int i0 = j + gh;
            const int i1 = j + 4 + gh;
            const int s0 = __shfl(px, i0);
            const int s1 = __shfl(px, i1);
            const ushort8 r0 = *(const ushort8*)(hb + (size_t)s0 * INF + hcol);
            const ushort8 r1 = *(const ushort8*)(hb + (size_t)s1 * INF + hcol);
            const float w0 = (i0 < m) ? 1.f : 0.f;
            const float w1 = (i1 < m) ? 1.f : 0.f;
            const int ee = __shfl(py, j + ge);
            const float4 fv = *(const float4*)(eftr + (size_t)ee * EF + ecol);
            const float we = (j + ge < m) ? 1.f : 0.f;
#pragma unroll
            for (int i = 0; i < 8; ++i) {
                ah[i] = fmaf(w0, bf2f(r0[i]), ah[i]);
                ah[i] = fmaf(w1, bf2f(r1[i]), ah[i]);
            }
            ae.x = fmaf(we, fv.x, ae.x);
            ae.y = fmaf(we, fv.y, ae.y);
            ae.z = fmaf(we, fv.z, ae.z);
            ae.w = fmaf(we, fv.w, ae.w);
        }
    }

#pragma unroll
    for (int i = 0; i < 8; ++i) {
        ah[i] += __shfl_xor(ah[i], 16);
        ah[i] += __shfl_xor(ah[i], 32);
    }
#pragma unroll
    for (int d = 8; d <= 32; d <<= 1) {
        ae.x += __shfl_xor(ae.x, d); ae.y += __shfl_xor(ae.y, d);
        ae.z += __shfl_xor(ae.z, d); ae.w += __shfl_xor(ae.w, d);
    }

    const float inv = 1.f / fmaxf((float)(end - start), 1.f);
    if (lane < 16) {
        ushort8 o;
#pragma unroll
        for (int i = 0; i < 8; ++i) o[i] = f2bf(ah[i] * inv);
        *(ushort8*)(mean_h + (size_t)node * INF + lane * 8) = o;
    }
    if (lane < 8) {
        ushort4v o;
        o[0] = f2bf(ae.x * inv); o[1] = f2bf(ae.y * inv);
        o[2] = f2bf(ae.z * inv); o[3] = f2bf(ae.w * inv);
        *(ushort4v*)(mean_e + (size_t)node * EF + ecol) = o;
    }
}

// ---------------------------------------------------------------------------
// Node GEMM via MFMA (bf16 in, fp32 acc). LDS-free, barrier-free.
// Wave owns 16 nodes x 128 cols, K=288 in 9 chunks. All A-frags are now
// direct b128 bf16 loads (hb for kb<4, means otherwise).
// ---------------------------------------------------------------------------
__global__ __launch_bounds__(256)
void node_gemm_kernel(const unsigned short* __restrict__ hb,
                      const unsigned short* __restrict__ mean_h,
                      const unsigned short* __restrict__ mean_e,
                      const unsigned short* __restrict__ Mb,
                      const float* __restrict__ cvec,
                      float* __restrict__ out) {
    const int tid = threadIdx.x;
    const int lane = tid & 63;
    const int wid = tid >> 6;
    const int nt = blockIdx.x * 4 + wid;     // 16-node tile id
    const int m16 = lane & 15;
    const int quad = lane >> 4;
    const int koff = quad * 8;

    const int anode = nt * 16 + m16;
    const int nclamp = (anode < NN) ? anode : (NN - 1);

    float4v acc[8] = {};

    for (int kb = 0; kb < 9; ++kb) {
        short8 a;
        if (kb < 4)
            a = *(const short8*)(hb + (size_t)nclamp * INF + kb * 32 + koff);
        else if (kb < 8)
            a = *(const short8*)(mean_h + (size_t)nclamp * INF + (kb - 4) * 32 + koff);
        else
            a = *(const short8*)(mean_e + (size_t)nclamp * EF + koff);

        const short8* bp = (const short8*)(Mb + (size_t)kb * 8 * 64 * 8);
#pragma unroll
        for (int ct = 0; ct < 8; ++ct) {
            const short8 b = bp[ct * 64 + lane];
            acc[ct] = __builtin_amdgcn_mfma_f32_16x16x32_bf16(a, b, acc[ct], 0, 0, 0);
        }
    }

    float cv[8];
#pragma unroll
    for (int ct = 0; ct < 8; ++ct) cv[ct] = cvec[ct * 16 + m16];

#pragma unroll
    for (int r = 0; r < 4; ++r) {
        const int nrow = nt * 16 + quad * 4 + r;
        if (nrow < NN) {
            float* orow = out + (size_t)nrow * OUTF;
#pragma unroll
            for (int ct = 0; ct < 8; ++ct)
                orow[ct * 16 + m16] = acc[ct][r] + cv[ct];
        }
    }
}

extern "C" void kernel_launch(void* const* d_in, const int* in_sizes, int n_in,
                              void* d_out, int out_size, void* d_ws, size_t ws_size,
                              hipStream_t stream) {
    const float* h      = (const float*)d_in[0];
    const float* eftr   = (const float*)d_in[1];
    const float* weight = (const float*)d_in[2];
    const float* W_w    = (const float*)d_in[3];
    const float* W_b    = (const float*)d_in[4];
    const float* bias   = (const float*)d_in[5];
    const int*   src    = (const int*)d_in[6];
    const int*   dst    = (const int*)d_in[7];
    float* out = (float*)d_out;

    // workspace layout:
    char* p = (char*)d_ws;
    unsigned short* hb     = (unsigned short*)p;  p += (size_t)NN * INF * 2;   // 12.8 MB
    unsigned short* mean_h = (unsigned short*)p;  p += (size_t)NN * INF * 2;   // 12.8 MB
    unsigned short* mean_e = (unsigned short*)p;  p += (size_t)NN * EF * 2;    // 3.2 MB
    unsigned short* Mb     = (unsigned short*)p;  p += (size_t)KDIM * OUTF * 2;
    float*          cvec   = (float*)p;           p += OUTF * 4;
    int*            off    = (int*)p;             p += (size_t)NN * 4;
    int2*           eo2    = (int2*)p;            p += (size_t)NE * 8;
    int*            partial= (int*)p;
    // total ≈ 35.6 MB

    h2bf_kernel<<<3125, 256, 0, stream>>>(h, hb);
    prep_pack_kernel<<<269, 64, 0, stream>>>(weight, W_w, W_b, bias, Mb, cvec, off);
    hist_kernel<<<(NE + 255) / 256, 256, 0, stream>>>(dst, off);
    scan1_kernel<<<NBLK, 256, 0, stream>>>(off, partial);
    scan3_kernel<<<NBLK, 256, 0, stream>>>(off, partial);
    scatter_ids_kernel<<<(NE + 255) / 256, 256, 0, stream>>>(src, dst, off, eo2);
    gather_kernel<<<(NN + 3) / 4, 256, 0, stream>>>(hb, eftr, off, eo2,
                                                    mean_h, mean_e);
    node_gemm_kernel<<<(NN / 64) + 1, 256, 0, stream>>>(hb, mean_h, mean_e,
                                                        Mb, cvec, out);
}